// Round 1
// 600.518 us; speedup vs baseline: 1.2592x; 1.2592x over previous
//
#include <hip/hip_runtime.h>
#include <cmath>

#define BATCH 32
#define CIN   512
#define BR    256
#define LEN   4096
#define TL    32        // output positions per block (16-aligned -> aligned stores)
#define ROWS  34        // TL + 2 halo rows (l0-1 .. l0+32)
#define RS    264       // LDS row stride (bf16 elements), 256 + 8 pad
#define NBLK  128       // LEN / TL exactly

typedef __attribute__((ext_vector_type(8))) short bf16x8;
typedef __attribute__((ext_vector_type(4))) float f32x4;

#define MFMA_BF16(a,b,c) __builtin_amdgcn_mfma_f32_16x16x32_bf16((a),(b),(c),0,0,0)

__device__ __forceinline__ float bf2f(unsigned short h){
  union { unsigned int u; float f; } c; c.u = ((unsigned int)h) << 16; return c.f;
}
__device__ __forceinline__ unsigned short f2bf(float f){
  union { float f; unsigned int u; } c; c.f = f;
  unsigned int r = c.u + 0x7fffu + ((c.u >> 16) & 1u);   // RNE
  return (unsigned short)(r >> 16);
}
// mish(x) = x*tanh(softplus(x)) = x*u/(u+2), u = p*(p+2), p = e^x (clamped).
__device__ __forceinline__ float mish_f(float v){
  float p = __expf(fminf(v, 40.0f));
  float u = p * (p + 2.0f);
  return v * (u / (u + 2.0f));
}
__device__ __forceinline__ void unpack8(const uint4 v, float* f){
  f[0] = bf2f((unsigned short)(v.x & 0xffffu)); f[1] = bf2f((unsigned short)(v.x >> 16));
  f[2] = bf2f((unsigned short)(v.y & 0xffffu)); f[3] = bf2f((unsigned short)(v.y >> 16));
  f[4] = bf2f((unsigned short)(v.z & 0xffffu)); f[5] = bf2f((unsigned short)(v.z >> 16));
  f[6] = bf2f((unsigned short)(v.w & 0xffffu)); f[7] = bf2f((unsigned short)(v.w >> 16));
}

// ---------------- prep: fold BN, transpose w2, convert W1/W3 to bf16 (into d_ws) --------------
// folds layout (floats): [0]=a1 [256]=b1 [512]=a2 [768]=b2 [1024]=a3 [1280]=b3
//                        [1536]=w2 tap0 [1792]=tap1 [2048]=tap2
__global__ void prep_kernel(const float* __restrict__ w1, const float* __restrict__ w2,
                            const float* __restrict__ w3,
                            const float* __restrict__ b1w, const float* __restrict__ b1b,
                            const float* __restrict__ b1rm, const float* __restrict__ b1rv,
                            const float* __restrict__ b2w, const float* __restrict__ b2b,
                            const float* __restrict__ b2rm, const float* __restrict__ b2rv,
                            const float* __restrict__ b3w, const float* __restrict__ b3b,
                            const float* __restrict__ b3rm, const float* __restrict__ b3rv,
                            unsigned short* __restrict__ w1bf, unsigned short* __restrict__ w3bf,
                            float* __restrict__ folds)
{
  const int g = blockIdx.x * 256 + threadIdx.x;   // 256 blocks x 256 thr = 65536 = 256*256
  w1bf[g] = f2bf(w1[g]);
  w3bf[g] = f2bf(w3[g]);
  if (blockIdx.x == 0) {
    const int c = threadIdx.x;
    float a1 = b1w[c] / sqrtf(b1rv[c] + 1e-5f);
    folds[c]        = a1; folds[256 + c]  = b1b[c] - b1rm[c] * a1;
    float a2 = b2w[c] / sqrtf(b2rv[c] + 1e-5f);
    folds[512 + c]  = a2; folds[768 + c]  = b2b[c] - b2rm[c] * a2;
    float a3 = b3w[c] / sqrtf(b3rv[c] + 1e-5f);
    folds[1024 + c] = a3; folds[1280 + c] = b3b[c] - b3rm[c] * a3;
    folds[1536 + c] = w2[c * 3 + 0];
    folds[1792 + c] = w2[c * 3 + 1];
    folds[2048 + c] = w2[c * 3 + 2];
  }
}

// ---------------- main fused kernel ----------------
// LDS 35.9 KB -> 4 blocks/CU (16 waves/CU). mi-outer GEMM keeps only af[8] (32 VGPR) live.
__global__ __launch_bounds__(256, 4)
void fused_main(const float* __restrict__ xg,
                const int*   __restrict__ maskg,
                const unsigned short* __restrict__ w1bf,
                const unsigned short* __restrict__ w3bf,
                const float* __restrict__ fa1, const float* __restrict__ fb1,
                const float* __restrict__ fa2, const float* __restrict__ fb2,
                const float* __restrict__ fa3, const float* __restrict__ fb3,
                const float* __restrict__ w2p,
                float*       __restrict__ outg)
{
  __shared__ __align__(16) unsigned short ls_x2[ROWS * RS];   // x2 tile [row][ch]; reused as t2
  __shared__ __align__(16) unsigned short ls_t1[ROWS * RS];   // t1 tile [row][ch]

  const int tid = threadIdx.x;
  const int bx  = blockIdx.x;          // l-tile 0..127
  const int b   = blockIdx.y;          // batch
  const int l0  = bx * TL;             // 16-aligned

  // ---------- embedded x1 -> odd output channels (f32 bit copy, float4, grid-stride) ----------
  {
    const size_t nchunks = (size_t)BATCH * BR * LEN / 4;          // 8,388,608
    const size_t stride  = (size_t)NBLK * BATCH * 256;            // 1,048,576 -> exactly 8 iters
    for (size_t idx = ((size_t)b * NBLK + bx) * 256 + tid; idx < nchunks; idx += stride) {
      const int l  = (int)((idx & 1023) * 4);
      const int c  = (int)((idx >> 10) & 255);
      const int bb = (int)(idx >> 18);
      const float4 v = *(const float4*)(xg + (size_t)(bb * CIN + c) * LEN + l);
      *(float4*)(outg + (size_t)(bb * CIN + 2 * c + 1) * LEN + l) = v;
    }
  }

  // ---------- zero-init x2 tile only on edge blocks (rows with OOB l stay 0) ----------
  if (bx == 0 || bx == NBLK - 1) {
    uint4* z = (uint4*)ls_x2;
    const uint4 zz = make_uint4(0, 0, 0, 0);
    for (int i = tid; i < (ROWS * RS) / 8; i += 256) z[i] = zz;   // 1122 uint4 = whole tile
  }
  __syncthreads();

  // ---------- stage x2 (f32) -> LDS bf16, transposed [row][ch] ----------
  // 10 float4 chunks per channel cover l in [l0-4, l0+36) ⊇ [l0-1, l0+32].
  // Clamped chunks duplicate identical values; rows whose true l is OOB stay zero.
  {
    const int lbase4 = l0 - 4;
    for (int q = tid; q < 256 * 10; q += 256) {
      const int c   = q / 10;
      const int j   = q - c * 10;
      const int lg  = lbase4 + j * 4;
      const int lgc = min(max(lg, 0), LEN - 4);
      const float4 v = *(const float4*)(xg + (size_t)(b * CIN + BR + c) * LEN + lgc);
      const float vv[4] = {v.x, v.y, v.z, v.w};
      #pragma unroll
      for (int jj = 0; jj < 4; ++jj) {
        const int p = (lgc + jj) - (l0 - 1);
        if (p >= 0 && p < ROWS) ls_x2[p * RS + c] = f2bf(vv[jj]);
      }
    }
  }
  __syncthreads();

  const int lane = tid & 63;
  const int wid  = tid >> 6;     // wave 0..3
  const int xl   = lane & 15;    // MFMA m/n index
  const int qd   = lane >> 4;    // MFMA quad

  // ---------- GEMM1: t1 = mask*bn1(mish(W1 @ x2)) -> ls_t1 [row][ch] ----------
  // 3 j-groups: rows 0..15, 16..31, {32,33} (third group 2/16 useful, covers conv halo).
  {
    int mk1[3];
    #pragma unroll
    for (int j = 0; j < 3; ++j) {
      const int p = 16 * j + xl;
      const int l = l0 - 1 + p;
      mk1[j] = (p < ROWS && l >= 0 && l < LEN) ? maskg[b * LEN + l] : 0;
    }
    #pragma unroll
    for (int mi = 0; mi < 4; ++mi) {
      const int ob = (wid * 4 + mi) * 16;
      bf16x8 af[8];                       // W1 bf16 fragments, direct 16B loads (L2-hot)
      #pragma unroll
      for (int k = 0; k < 8; ++k)
        af[k] = *(const bf16x8*)&w1bf[(size_t)(ob + xl) * 256 + k * 32 + qd * 8];
      const f32x4 av = *(const f32x4*)&fa1[ob + 4 * qd];
      const f32x4 bv = *(const f32x4*)&fb1[ob + 4 * qd];
      #pragma unroll
      for (int j = 0; j < 3; ++j) {
        const int p  = 16 * j + xl;
        const int rp = min(p, ROWS - 1);   // j=2 lanes xl>=2 read duplicate row (discarded)
        bf16x8 bfr[8];
        #pragma unroll
        for (int k = 0; k < 8; ++k)
          bfr[k] = *(const bf16x8*)&ls_x2[rp * RS + k * 32 + qd * 8];
        f32x4 acc = {0.f, 0.f, 0.f, 0.f};
        #pragma unroll
        for (int k = 0; k < 8; ++k) acc = MFMA_BF16(af[k], bfr[k], acc);
        unsigned short us[4];
        #pragma unroll
        for (int r = 0; r < 4; ++r) {
          float v = mish_f(acc[r]);
          v = av[r] * v + bv[r];
          if (!mk1[j]) v = 0.0f;
          us[r] = f2bf(v);
        }
        if (p < ROWS) {
          const unsigned int lo = (unsigned int)us[0] | ((unsigned int)us[1] << 16);
          const unsigned int hi = (unsigned int)us[2] | ((unsigned int)us[3] << 16);
          *(uint2*)&ls_t1[p * RS + ob + 4 * qd] = make_uint2(lo, hi);
        }
      }
    }
  }
  __syncthreads();

  // ---------- depthwise conv3 + bn2 + mask: t1 -> t2 (reuse ls_x2), rows 0..31 ----------
  {
    const int c0    = (tid & 31) * 8;
    const int qbase = tid >> 5;
    const f32x4 k0a = *(const f32x4*)&w2p[      c0], k0b = *(const f32x4*)&w2p[      c0 + 4];
    const f32x4 k1a = *(const f32x4*)&w2p[256 + c0], k1b = *(const f32x4*)&w2p[256 + c0 + 4];
    const f32x4 k2a = *(const f32x4*)&w2p[512 + c0], k2b = *(const f32x4*)&w2p[512 + c0 + 4];
    const f32x4 a2a = *(const f32x4*)&fa2[c0],       a2b = *(const f32x4*)&fa2[c0 + 4];
    const f32x4 b2a = *(const f32x4*)&fb2[c0],       b2b = *(const f32x4*)&fb2[c0 + 4];
    #pragma unroll
    for (int it = 0; it < 4; ++it) {
      const int qo = qbase + 8 * it;      // 0..31, each (qo,c0) exactly once
      const int mk = maskg[b * LEN + l0 + qo];   // l0+qo <= 4095 always
      const uint4 ra = *(const uint4*)&ls_t1[(qo    ) * RS + c0];
      const uint4 rb = *(const uint4*)&ls_t1[(qo + 1) * RS + c0];
      const uint4 rc = *(const uint4*)&ls_t1[(qo + 2) * RS + c0];
      float ta[8], tb[8], tc[8];
      unpack8(ra, ta); unpack8(rb, tb); unpack8(rc, tc);
      unsigned short us[8];
      #pragma unroll
      for (int i = 0; i < 4; ++i) {
        float y  = a2a[i] * (k0a[i] * ta[i]     + k1a[i] * tb[i]     + k2a[i] * tc[i]    ) + b2a[i];
        float y2 = a2b[i] * (k0b[i] * ta[4 + i] + k1b[i] * tb[4 + i] + k2b[i] * tc[4 + i]) + b2b[i];
        if (!mk) { y = 0.0f; y2 = 0.0f; }
        us[i]     = f2bf(y);
        us[4 + i] = f2bf(y2);
      }
      uint4 wv;
      wv.x = (unsigned int)us[0] | ((unsigned int)us[1] << 16);
      wv.y = (unsigned int)us[2] | ((unsigned int)us[3] << 16);
      wv.z = (unsigned int)us[4] | ((unsigned int)us[5] << 16);
      wv.w = (unsigned int)us[6] | ((unsigned int)us[7] << 16);
      *(uint4*)&ls_x2[qo * RS + c0] = wv;
    }
  }
  __syncthreads();

  // ---------- GEMM2 (operand-swapped): D[m=pos][n=ch] = t2 @ W3^T ----------
  // Each lane owns channel ob+xl at 4 consecutive l (l0+16j+4qd+r) -> aligned float4 store.
  {
    int4 mku[2];
    #pragma unroll
    for (int j = 0; j < 2; ++j)
      mku[j] = *(const int4*)&maskg[b * LEN + l0 + 16 * j + 4 * qd];
    #pragma unroll
    for (int mi = 0; mi < 4; ++mi) {
      const int ob = (wid * 4 + mi) * 16;
      bf16x8 af[8];                       // W3 bf16 fragments (B operand: n=xl, k-slice qd)
      #pragma unroll
      for (int k = 0; k < 8; ++k)
        af[k] = *(const bf16x8*)&w3bf[(size_t)(ob + xl) * 256 + k * 32 + qd * 8];
      const float a3v = fa3[ob + xl];
      const float b3v = fb3[ob + xl];
      #pragma unroll
      for (int j = 0; j < 2; ++j) {
        bf16x8 ta2[8];                    // t2 fragments (A operand: m=xl row, k-slice qd)
        #pragma unroll
        for (int k = 0; k < 8; ++k)
          ta2[k] = *(const bf16x8*)&ls_x2[(16 * j + xl) * RS + k * 32 + qd * 8];
        f32x4 acc = {0.f, 0.f, 0.f, 0.f};
        #pragma unroll
        for (int k = 0; k < 8; ++k) acc = MFMA_BF16(ta2[k], af[k], acc);
        const int4 mk = mku[j];
        const int mks[4] = {mk.x, mk.y, mk.z, mk.w};
        float4 ov;
        float* op = &ov.x;
        #pragma unroll
        for (int r = 0; r < 4; ++r) {
          float v = mish_f(acc[r]);
          v = a3v * v + b3v;
          if (!mks[r]) v = 0.0f;
          op[r] = v;
        }
        *(float4*)&outg[(size_t)(b * CIN + 2 * (ob + xl)) * LEN + l0 + 16 * j + 4 * qd] = ov;
      }
    }
  }
}

extern "C" void kernel_launch(void* const* d_in, const int* in_sizes, int n_in,
                              void* d_out, int out_size, void* d_ws, size_t ws_size,
                              hipStream_t stream) {
  (void)in_sizes; (void)n_in; (void)out_size; (void)ws_size;
  const float* xg    = (const float*)d_in[0];
  const int*   maskg = (const int*)d_in[1];
  const float* w1    = (const float*)d_in[2];
  const float* w2    = (const float*)d_in[3];
  const float* w3    = (const float*)d_in[4];
  const float* b1w   = (const float*)d_in[5];
  const float* b1b   = (const float*)d_in[6];
  const float* b1rm  = (const float*)d_in[7];
  const float* b1rv  = (const float*)d_in[8];
  const float* b2w   = (const float*)d_in[9];
  const float* b2b   = (const float*)d_in[10];
  const float* b2rm  = (const float*)d_in[11];
  const float* b2rv  = (const float*)d_in[12];
  const float* b3w   = (const float*)d_in[13];
  const float* b3b   = (const float*)d_in[14];
  const float* b3rm  = (const float*)d_in[15];
  const float* b3rv  = (const float*)d_in[16];
  float* outp = (float*)d_out;

  // workspace carve: w1bf (128 KiB) | w3bf (128 KiB) | folds (9 KiB)
  unsigned short* w1bf = (unsigned short*)d_ws;
  unsigned short* w3bf = (unsigned short*)((char*)d_ws + 131072);
  float*          folds = (float*)((char*)d_ws + 262144);

  hipLaunchKernelGGL(prep_kernel, dim3(256), dim3(256), 0, stream,
                     w1, w2, w3,
                     b1w, b1b, b1rm, b1rv, b2w, b2b, b2rm, b2rv, b3w, b3b, b3rm, b3rv,
                     w1bf, w3bf, folds);

  hipLaunchKernelGGL(fused_main, dim3(NBLK, BATCH, 1), dim3(256, 1, 1), 0, stream,
                     xg, maskg, w1bf, w3bf,
                     folds, folds + 256,          // a1, b1
                     folds + 512, folds + 768,    // a2, b2
                     folds + 1024, folds + 1280,  // a3, b3
                     folds + 1536,                // w2 taps [3][256]
                     outp);
}

// Round 2
// 595.913 us; speedup vs baseline: 1.2689x; 1.0077x over previous
//
#include <hip/hip_runtime.h>
#include <cmath>

#define BATCH 32
#define CIN   512
#define BR    256
#define LEN   4096
#define TL    32        // output positions per block (16-aligned -> aligned stores)
#define ROWS  34        // TL + 2 halo rows (l0-1 .. l0+32)
#define RS    264       // LDS row stride (bf16 elements), 256 + 8 pad
#define NBLK  128       // LEN / TL exactly

typedef __attribute__((ext_vector_type(8))) short bf16x8;
typedef __attribute__((ext_vector_type(4))) float f32x4;

#define MFMA_BF16(a,b,c) __builtin_amdgcn_mfma_f32_16x16x32_bf16((a),(b),(c),0,0,0)

__device__ __forceinline__ float bf2f(unsigned short h){
  union { unsigned int u; float f; } c; c.u = ((unsigned int)h) << 16; return c.f;
}
__device__ __forceinline__ unsigned short f2bf(float f){
  union { float f; unsigned int u; } c; c.f = f;
  unsigned int r = c.u + 0x7fffu + ((c.u >> 16) & 1u);   // RNE
  return (unsigned short)(r >> 16);
}
// mish(x) = x*tanh(softplus(x)) = x*u/(u+2), u = p*(p+2), p = e^x (clamped).
__device__ __forceinline__ float mish_f(float v){
  float p = __expf(fminf(v, 40.0f));
  float u = p * (p + 2.0f);
  return v * (u / (u + 2.0f));
}
__device__ __forceinline__ void unpack8(const uint4 v, float* f){
  f[0] = bf2f((unsigned short)(v.x & 0xffffu)); f[1] = bf2f((unsigned short)(v.x >> 16));
  f[2] = bf2f((unsigned short)(v.y & 0xffffu)); f[3] = bf2f((unsigned short)(v.y >> 16));
  f[4] = bf2f((unsigned short)(v.z & 0xffffu)); f[5] = bf2f((unsigned short)(v.z >> 16));
  f[6] = bf2f((unsigned short)(v.w & 0xffffu)); f[7] = bf2f((unsigned short)(v.w >> 16));
}

// ---------------- prep: fold BN, transpose w2, convert W1/W3 to bf16 (into d_ws) --------------
// folds layout (floats): [0]=a1 [256]=b1 [512]=a2 [768]=b2 [1024]=a3 [1280]=b3
//                        [1536]=w2 tap0 [1792]=tap1 [2048]=tap2
__global__ void prep_kernel(const float* __restrict__ w1, const float* __restrict__ w2,
                            const float* __restrict__ w3,
                            const float* __restrict__ b1w, const float* __restrict__ b1b,
                            const float* __restrict__ b1rm, const float* __restrict__ b1rv,
                            const float* __restrict__ b2w, const float* __restrict__ b2b,
                            const float* __restrict__ b2rm, const float* __restrict__ b2rv,
                            const float* __restrict__ b3w, const float* __restrict__ b3b,
                            const float* __restrict__ b3rm, const float* __restrict__ b3rv,
                            unsigned short* __restrict__ w1bf, unsigned short* __restrict__ w3bf,
                            float* __restrict__ folds)
{
  const int g = blockIdx.x * 256 + threadIdx.x;   // 256 blocks x 256 thr = 65536 = 256*256
  w1bf[g] = f2bf(w1[g]);
  w3bf[g] = f2bf(w3[g]);
  if (blockIdx.x == 0) {
    const int c = threadIdx.x;
    float a1 = b1w[c] / sqrtf(b1rv[c] + 1e-5f);
    folds[c]        = a1; folds[256 + c]  = b1b[c] - b1rm[c] * a1;
    float a2 = b2w[c] / sqrtf(b2rv[c] + 1e-5f);
    folds[512 + c]  = a2; folds[768 + c]  = b2b[c] - b2rm[c] * a2;
    float a3 = b3w[c] / sqrtf(b3rv[c] + 1e-5f);
    folds[1024 + c] = a3; folds[1280 + c] = b3b[c] - b3rm[c] * a3;
    folds[1536 + c] = w2[c * 3 + 0];
    folds[1792 + c] = w2[c * 3 + 1];
    folds[2048 + c] = w2[c * 3 + 2];
  }
}

// ---------------- x1 bit-copy -> odd output channels (pure streaming memcpy) ----------------
// block k copies one full channel row: xg[bb][c][:] -> outg[bb][2c+1][:], 16 KB each way.
__global__ __launch_bounds__(256)
void copy_x1_kernel(const float* __restrict__ xg, float* __restrict__ outg)
{
  const int k  = blockIdx.x;            // 8192 = 32 * 256
  const int bb = k >> 8;
  const int c  = k & 255;
  const float4* __restrict__ src = (const float4*)(xg  + (size_t)(bb * CIN + c)         * LEN);
  float4*       __restrict__ dst = (float4*)      (outg + (size_t)(bb * CIN + 2 * c + 1) * LEN);
  const int t = threadIdx.x;
  const float4 v0 = src[t];
  const float4 v1 = src[t + 256];
  const float4 v2 = src[t + 512];
  const float4 v3 = src[t + 768];
  dst[t]       = v0;
  dst[t + 256] = v1;
  dst[t + 512] = v2;
  dst[t + 768] = v3;
}

// ---------------- main fused kernel (x2 path only) ----------------
// LDS 36 KB -> 4 blocks/CU (16 waves/CU). mi-outer GEMMs keep weight regs minimal.
__global__ __launch_bounds__(256, 4)
void fused_main(const float* __restrict__ xg,
                const int*   __restrict__ maskg,
                const unsigned short* __restrict__ w1bf,
                const unsigned short* __restrict__ w3bf,
                const float* __restrict__ fa1, const float* __restrict__ fb1,
                const float* __restrict__ fa2, const float* __restrict__ fb2,
                const float* __restrict__ fa3, const float* __restrict__ fb3,
                const float* __restrict__ w2p,
                float*       __restrict__ outg)
{
  __shared__ __align__(16) unsigned short ls_x2[ROWS * RS];   // x2 tile [row][ch]; reused as t2
  __shared__ __align__(16) unsigned short ls_t1[ROWS * RS];   // t1 tile [row][ch]
  __shared__ int ls_mk[48];                                   // mask window l0-1..l0+32, 0-padded

  const int tid = threadIdx.x;
  const int bx  = blockIdx.x;          // l-tile 0..127
  const int b   = blockIdx.y;          // batch
  const int l0  = bx * TL;             // 16-aligned

  // ---------- issue all 10 staging loads first (latency hides under init below) ----------
  float4 stg[10];
  #pragma unroll
  for (int it = 0; it < 10; ++it) {
    const int q   = tid + 256 * it;
    const int c   = q / 10;
    const int j   = q - 10 * c;
    const int lg  = l0 - 4 + 4 * j;
    const int lgc = min(max(lg, 0), LEN - 4);
    stg[it] = *(const float4*)(xg + (size_t)(b * CIN + BR + c) * LEN + lgc);
  }

  // ---------- zero-init x2 tile only on edge blocks (rows with OOB l stay 0) ----------
  if (bx == 0 || bx == NBLK - 1) {
    uint4* z = (uint4*)ls_x2;
    const uint4 zz = make_uint4(0, 0, 0, 0);
    for (int i = tid; i < (ROWS * RS) / 8; i += 256) z[i] = zz;
  }
  // ---------- mask window -> LDS (entries beyond ROWS or OOB l are 0) ----------
  if (tid < 48) {
    const int l = l0 - 1 + tid;
    ls_mk[tid] = (tid < ROWS && l >= 0 && l < LEN) ? maskg[b * LEN + l] : 0;
  }
  __syncthreads();

  // ---------- convert + store staged x2 -> LDS bf16, transposed [row][ch] ----------
  // Clamped chunks duplicate identical values; rows whose true l is OOB stay zero.
  #pragma unroll
  for (int it = 0; it < 10; ++it) {
    const int q   = tid + 256 * it;
    const int c   = q / 10;
    const int j   = q - 10 * c;
    const int lg  = l0 - 4 + 4 * j;
    const int lgc = min(max(lg, 0), LEN - 4);
    const float vv[4] = {stg[it].x, stg[it].y, stg[it].z, stg[it].w};
    #pragma unroll
    for (int jj = 0; jj < 4; ++jj) {
      const int p = (lgc + jj) - (l0 - 1);
      if (p >= 0 && p < ROWS) ls_x2[p * RS + c] = f2bf(vv[jj]);
    }
  }
  __syncthreads();

  const int lane = tid & 63;
  const int wid  = tid >> 6;     // wave 0..3
  const int xl   = lane & 15;    // MFMA m/n index
  const int qd   = lane >> 4;    // MFMA quad

  // ---------- GEMM1: t1 = mask*bn1(mish(W1 @ x2)) -> ls_t1 [row][ch] ----------
  // 3 j-groups: rows 0..15, 16..31, {32,33} (third group 2/16 useful, covers conv halo).
  {
    int mk1[3];
    #pragma unroll
    for (int j = 0; j < 3; ++j)
      mk1[j] = ls_mk[16 * j + xl];          // rows >= ROWS read padded zeros
    #pragma unroll
    for (int mi = 0; mi < 4; ++mi) {
      const int ob = (wid * 4 + mi) * 16;
      bf16x8 af[8];                          // W1 bf16 fragments, direct 16B loads (L2-hot)
      #pragma unroll
      for (int k = 0; k < 8; ++k)
        af[k] = *(const bf16x8*)&w1bf[(size_t)(ob + xl) * 256 + k * 32 + qd * 8];
      const f32x4 av = *(const f32x4*)&fa1[ob + 4 * qd];
      const f32x4 bv = *(const f32x4*)&fb1[ob + 4 * qd];
      #pragma unroll
      for (int j = 0; j < 3; ++j) {
        const int p  = 16 * j + xl;
        const int rp = min(p, ROWS - 1);     // j=2 lanes xl>=2 read duplicate row (discarded)
        bf16x8 bfr[8];
        #pragma unroll
        for (int k = 0; k < 8; ++k)
          bfr[k] = *(const bf16x8*)&ls_x2[rp * RS + k * 32 + qd * 8];
        f32x4 acc = {0.f, 0.f, 0.f, 0.f};
        #pragma unroll
        for (int k = 0; k < 8; ++k) acc = MFMA_BF16(af[k], bfr[k], acc);
        unsigned short us[4];
        #pragma unroll
        for (int r = 0; r < 4; ++r) {
          float v = mish_f(acc[r]);
          v = av[r] * v + bv[r];
          if (!mk1[j]) v = 0.0f;
          us[r] = f2bf(v);
        }
        if (p < ROWS) {
          const unsigned int lo = (unsigned int)us[0] | ((unsigned int)us[1] << 16);
          const unsigned int hi = (unsigned int)us[2] | ((unsigned int)us[3] << 16);
          *(uint2*)&ls_t1[p * RS + ob + 4 * qd] = make_uint2(lo, hi);
        }
      }
    }
  }
  __syncthreads();

  // ---------- depthwise conv3 + bn2 + mask: t1 -> t2 (reuse ls_x2), rows 0..31 ----------
  {
    const int c0    = (tid & 31) * 8;
    const int qbase = tid >> 5;
    const f32x4 k0a = *(const f32x4*)&w2p[      c0], k0b = *(const f32x4*)&w2p[      c0 + 4];
    const f32x4 k1a = *(const f32x4*)&w2p[256 + c0], k1b = *(const f32x4*)&w2p[256 + c0 + 4];
    const f32x4 k2a = *(const f32x4*)&w2p[512 + c0], k2b = *(const f32x4*)&w2p[512 + c0 + 4];
    const f32x4 a2a = *(const f32x4*)&fa2[c0],       a2b = *(const f32x4*)&fa2[c0 + 4];
    const f32x4 b2a = *(const f32x4*)&fb2[c0],       b2b = *(const f32x4*)&fb2[c0 + 4];
    #pragma unroll
    for (int it = 0; it < 4; ++it) {
      const int qo = qbase + 8 * it;      // 0..31, each (qo,c0) exactly once
      const int mk = ls_mk[1 + qo];
      const uint4 ra = *(const uint4*)&ls_t1[(qo    ) * RS + c0];
      const uint4 rb = *(const uint4*)&ls_t1[(qo + 1) * RS + c0];
      const uint4 rc = *(const uint4*)&ls_t1[(qo + 2) * RS + c0];
      float ta[8], tb[8], tc[8];
      unpack8(ra, ta); unpack8(rb, tb); unpack8(rc, tc);
      unsigned short us[8];
      #pragma unroll
      for (int i = 0; i < 4; ++i) {
        float y  = a2a[i] * (k0a[i] * ta[i]     + k1a[i] * tb[i]     + k2a[i] * tc[i]    ) + b2a[i];
        float y2 = a2b[i] * (k0b[i] * ta[4 + i] + k1b[i] * tb[4 + i] + k2b[i] * tc[4 + i]) + b2b[i];
        if (!mk) { y = 0.0f; y2 = 0.0f; }
        us[i]     = f2bf(y);
        us[4 + i] = f2bf(y2);
      }
      uint4 wv;
      wv.x = (unsigned int)us[0] | ((unsigned int)us[1] << 16);
      wv.y = (unsigned int)us[2] | ((unsigned int)us[3] << 16);
      wv.z = (unsigned int)us[4] | ((unsigned int)us[5] << 16);
      wv.w = (unsigned int)us[6] | ((unsigned int)us[7] << 16);
      *(uint4*)&ls_x2[qo * RS + c0] = wv;
    }
  }
  __syncthreads();

  // ---------- GEMM2 (operand-swapped): D[m=pos][n=ch] = t2 @ W3^T ----------
  // Each lane owns channel ob+xl at 4 consecutive l (l0+16j+4qd+r) -> aligned float4 store.
  {
    int mks[2][4];
    #pragma unroll
    for (int j = 0; j < 2; ++j)
      #pragma unroll
      for (int r = 0; r < 4; ++r)
        mks[j][r] = ls_mk[1 + 16 * j + 4 * qd + r];
    #pragma unroll
    for (int mi = 0; mi < 4; ++mi) {
      const int ob = (wid * 4 + mi) * 16;
      bf16x8 af[8];                       // W3 bf16 fragments (B operand: n=xl, k-slice qd)
      #pragma unroll
      for (int k = 0; k < 8; ++k)
        af[k] = *(const bf16x8*)&w3bf[(size_t)(ob + xl) * 256 + k * 32 + qd * 8];
      const float a3v = fa3[ob + xl];
      const float b3v = fb3[ob + xl];
      #pragma unroll
      for (int j = 0; j < 2; ++j) {
        bf16x8 ta2[8];                    // t2 fragments (A operand: m=xl row, k-slice qd)
        #pragma unroll
        for (int k = 0; k < 8; ++k)
          ta2[k] = *(const bf16x8*)&ls_x2[(16 * j + xl) * RS + k * 32 + qd * 8];
        f32x4 acc = {0.f, 0.f, 0.f, 0.f};
        #pragma unroll
        for (int k = 0; k < 8; ++k) acc = MFMA_BF16(ta2[k], af[k], acc);
        float4 ov;
        float* op = &ov.x;
        #pragma unroll
        for (int r = 0; r < 4; ++r) {
          float v = mish_f(acc[r]);
          v = a3v * v + b3v;
          if (!mks[j][r]) v = 0.0f;
          op[r] = v;
        }
        *(float4*)&outg[(size_t)(b * CIN + 2 * (ob + xl)) * LEN + l0 + 16 * j + 4 * qd] = ov;
      }
    }
  }
}

extern "C" void kernel_launch(void* const* d_in, const int* in_sizes, int n_in,
                              void* d_out, int out_size, void* d_ws, size_t ws_size,
                              hipStream_t stream) {
  (void)in_sizes; (void)n_in; (void)out_size; (void)ws_size;
  const float* xg    = (const float*)d_in[0];
  const int*   maskg = (const int*)d_in[1];
  const float* w1    = (const float*)d_in[2];
  const float* w2    = (const float*)d_in[3];
  const float* w3    = (const float*)d_in[4];
  const float* b1w   = (const float*)d_in[5];
  const float* b1b   = (const float*)d_in[6];
  const float* b1rm  = (const float*)d_in[7];
  const float* b1rv  = (const float*)d_in[8];
  const float* b2w   = (const float*)d_in[9];
  const float* b2b   = (const float*)d_in[10];
  const float* b2rm  = (const float*)d_in[11];
  const float* b2rv  = (const float*)d_in[12];
  const float* b3w   = (const float*)d_in[13];
  const float* b3b   = (const float*)d_in[14];
  const float* b3rm  = (const float*)d_in[15];
  const float* b3rv  = (const float*)d_in[16];
  float* outp = (float*)d_out;

  // workspace carve: w1bf (128 KiB) | w3bf (128 KiB) | folds (9 KiB)
  unsigned short* w1bf = (unsigned short*)d_ws;
  unsigned short* w3bf = (unsigned short*)((char*)d_ws + 131072);
  float*          folds = (float*)((char*)d_ws + 262144);

  hipLaunchKernelGGL(prep_kernel, dim3(256), dim3(256), 0, stream,
                     w1, w2, w3,
                     b1w, b1b, b1rm, b1rv, b2w, b2b, b2rm, b2rv, b3w, b3b, b3rm, b3rv,
                     w1bf, w3bf, folds);

  hipLaunchKernelGGL(copy_x1_kernel, dim3(BATCH * BR), dim3(256, 1, 1), 0, stream,
                     xg, outp);

  hipLaunchKernelGGL(fused_main, dim3(NBLK, BATCH, 1), dim3(256, 1, 1), 0, stream,
                     xg, maskg, w1bf, w3bf,
                     folds, folds + 256,          // a1, b1
                     folds + 512, folds + 768,    // a2, b2
                     folds + 1024, folds + 1280,  // a3, b3
                     folds + 1536,                // w2 taps [3][256]
                     outp);
}